// Round 2
// baseline (269.766 us; speedup 1.0000x reference)
//
#include <hip/hip_runtime.h>
#include <hip/hip_bf16.h>
#include <cstdint>

// DenseMRConv: out = concat([x, max_k(x[idx[n,k]] - x[n])]) @ W + b
// N=100000, K=32, d=64, d_out=64.
//
// One wave per 16-node tile. Phase A: lane = feature chunk (float4),
// 4 lane-groups x 8 iterations cover the 32 neighbors; butterfly max.
// Phase B: h (bf16) -> LDS -> MFMA A-frags; W held in registers as
// B-frags (loaded once per wave); 16x16x32 bf16 MFMA, fp32 accumulate.
//
// NOTE: harness delivers integer inputs as int32 (edge_index is const int*,
// NOT long long — reading 8B caused the round-1 OOB fault).

typedef __attribute__((ext_vector_type(8))) short short8;
typedef __attribute__((ext_vector_type(4))) float f4;

#define TILE   16
#define WPB    4            // waves per block
#define ROWS   160          // padded h row stride in bf16 elems (320 B, 16B-aligned)

__device__ __forceinline__ unsigned short f2bf(float f) {
  unsigned int u = __builtin_bit_cast(unsigned int, f);
  u += 0x7fffu + ((u >> 16) & 1u);          // round-to-nearest-even
  return (unsigned short)(u >> 16);
}

__global__ __launch_bounds__(256, 4)
void mrconv_kernel(const float* __restrict__ x,
                   const int* __restrict__ ei,
                   const float* __restrict__ W,
                   const float* __restrict__ bias,
                   float* __restrict__ out,
                   int n_tiles)
{
  __shared__ __align__(16) unsigned short hs[WPB][TILE * ROWS];
  const int wave = threadIdx.x >> 6;
  const int lane = threadIdx.x & 63;
  const int c = lane & 15;     // feature chunk / col within 16-tile
  const int g = lane >> 4;     // quad group

  // ---- B fragments: W (fp32 -> bf16), resident in VGPRs for the whole wave.
  // B layout for mfma_f32_16x16x32_bf16: lane holds B[k=(l>>4)*8+j][n=l&15].
  short8 bfrag[4][4];
  #pragma unroll
  for (int ks = 0; ks < 4; ++ks) {
    #pragma unroll
    for (int nt = 0; nt < 4; ++nt) {
      short8 v;
      #pragma unroll
      for (int j = 0; j < 8; ++j) {
        int k = ks * 32 + g * 8 + j;
        v[j] = (short)f2bf(W[k * 64 + nt * 16 + c]);
      }
      bfrag[ks][nt] = v;
    }
  }

  const int tile = blockIdx.x * WPB + wave;
  if (tile >= n_tiles) return;
  const int node0 = tile * TILE;
  unsigned short* hrow = &hs[wave][0];

  // ---- Phase A: gather + running max, one node at a time (wave-serial).
  #pragma unroll 2
  for (int t = 0; t < TILE; ++t) {
    const int n = node0 + t;
    const f4 xi = *(const f4*)(x + n * 64 + 4 * c);
    f4 m = { -3.4e38f, -3.4e38f, -3.4e38f, -3.4e38f };
    #pragma unroll
    for (int it = 0; it < 8; ++it) {
      const int j = ei[n * 32 + it * 4 + g];   // group g's neighbor
      const f4 xj = *(const f4*)(x + j * 64 + 4 * c);
      m.x = fmaxf(m.x, xj.x - xi.x);
      m.y = fmaxf(m.y, xj.y - xi.y);
      m.z = fmaxf(m.z, xj.z - xi.z);
      m.w = fmaxf(m.w, xj.w - xi.w);
    }
    // butterfly max across the 4 groups (lanes ^16, ^32)
    m.x = fmaxf(m.x, __shfl_xor(m.x, 16));
    m.y = fmaxf(m.y, __shfl_xor(m.y, 16));
    m.z = fmaxf(m.z, __shfl_xor(m.z, 16));
    m.w = fmaxf(m.w, __shfl_xor(m.w, 16));
    m.x = fmaxf(m.x, __shfl_xor(m.x, 32));
    m.y = fmaxf(m.y, __shfl_xor(m.y, 32));
    m.z = fmaxf(m.z, __shfl_xor(m.z, 32));
    m.w = fmaxf(m.w, __shfl_xor(m.w, 32));

    // write h row t: [x | diff_max] as bf16
    if (g == 0) {
      ushort4 p;
      p.x = f2bf(xi.x); p.y = f2bf(xi.y); p.z = f2bf(xi.z); p.w = f2bf(xi.w);
      *(ushort4*)(hrow + t * ROWS + 4 * c) = p;
    } else if (g == 1) {
      ushort4 p;
      p.x = f2bf(m.x); p.y = f2bf(m.y); p.z = f2bf(m.z); p.w = f2bf(m.w);
      *(ushort4*)(hrow + t * ROWS + 64 + 4 * c) = p;
    }
  }

  // wave-internal LDS visibility (no inter-wave dependency -> no __syncthreads)
  __asm__ volatile("s_waitcnt lgkmcnt(0)" ::: "memory");

  // ---- Phase B: [16 x 128] @ [128 x 64] via 16 MFMAs.
  f4 acc[4] = {{0.f,0.f,0.f,0.f},{0.f,0.f,0.f,0.f},{0.f,0.f,0.f,0.f},{0.f,0.f,0.f,0.f}};
  #pragma unroll
  for (int ks = 0; ks < 4; ++ks) {
    // A layout: lane holds A[m=l&15][k=(l>>4)*8+j]
    short8 a = *(const short8*)(hrow + c * ROWS + ks * 32 + g * 8);
    #pragma unroll
    for (int nt = 0; nt < 4; ++nt)
      acc[nt] = __builtin_amdgcn_mfma_f32_16x16x32_bf16(a, bfrag[ks][nt], acc[nt], 0, 0, 0);
  }

  // ---- Epilogue: C/D layout col=lane&15, row=(lane>>4)*4+reg  [m89-verified]
  const int rbase = node0 + g * 4;
  #pragma unroll
  for (int nt = 0; nt < 4; ++nt) {
    const float bb = bias[nt * 16 + c];
    #pragma unroll
    for (int j = 0; j < 4; ++j) {
      out[(rbase + j) * 64 + nt * 16 + c] = acc[nt][j] + bb;
    }
  }
}

extern "C" void kernel_launch(void* const* d_in, const int* in_sizes, int n_in,
                              void* d_out, int out_size, void* d_ws, size_t ws_size,
                              hipStream_t stream) {
  const float* x  = (const float*)d_in[0];
  const int*   ei = (const int*)d_in[1];     // int64 in reference -> int32 here
  const float* W  = (const float*)d_in[2];
  const float* b  = (const float*)d_in[3];
  float* out = (float*)d_out;

  const int N = in_sizes[0] / 64;          // 100000
  const int n_tiles = N / TILE;            // 6250 (N % 16 == 0)
  const int blocks = (n_tiles + WPB - 1) / WPB;  // 1563

  hipLaunchKernelGGL(mrconv_kernel, dim3(blocks), dim3(256), 0, stream,
                     x, ei, W, b, out, n_tiles);
}

// Round 3
// 189.471 us; speedup vs baseline: 1.4238x; 1.4238x over previous
//
#include <hip/hip_runtime.h>
#include <hip/hip_bf16.h>
#include <cstdint>

// DenseMRConv: out = concat([x, max_k(x[idx[n,k]] - x[n])]) @ W + b
// N=100000, K=32, d=64, d_out=64.
//
// R3: gather from a bf16 copy of x (halves gather bytes, doubles rows/instr),
// ei tile staged in LDS (kills the ei->gather latency chain), epilogue staged
// through LDS for fully-coalesced 1KB stores (kills write amplification).
// x_i stays fp32 for the subtract; only x_j is bf16-rounded.

typedef __attribute__((ext_vector_type(8))) short short8;
typedef __attribute__((ext_vector_type(4))) float f4;

#define TILE 16
#define WPB  4
#define ROWS 160   // padded h row stride in bf16 elems (320 B)

__device__ __forceinline__ unsigned short f2bf(float f) {
  unsigned int u = __builtin_bit_cast(unsigned int, f);
  u += 0x7fffu + ((u >> 16) & 1u);          // round-to-nearest-even
  return (unsigned short)(u >> 16);
}
__device__ __forceinline__ unsigned int pack2(float a, float b) {
  return (unsigned int)f2bf(a) | ((unsigned int)f2bf(b) << 16);
}
__device__ __forceinline__ float bflo(unsigned int u) {
  return __builtin_bit_cast(float, u << 16);
}
__device__ __forceinline__ float bfhi(unsigned int u) {
  return __builtin_bit_cast(float, u & 0xffff0000u);
}

// ---- pass 1: x fp32 -> bf16 copy in workspace (each thread: 8 elems)
__global__ __launch_bounds__(256)
void convert_kernel(const float* __restrict__ x, unsigned int* __restrict__ xbf, int n8) {
  int i = blockIdx.x * 256 + threadIdx.x;
  if (i >= n8) return;
  const f4* p = (const f4*)x + (size_t)i * 2;
  f4 a = p[0], b = p[1];
  uint4 w;
  w.x = pack2(a.x, a.y); w.y = pack2(a.z, a.w);
  w.z = pack2(b.x, b.y); w.w = pack2(b.z, b.w);
  ((uint4*)xbf)[i] = w;
}

// ---- pass 2: gather + max + MFMA GEMM
__global__ __launch_bounds__(256, 4)
void mrconv_bf16_kernel(const float* __restrict__ x,
                        const unsigned int* __restrict__ xbf,  // 2 bf16 per uint
                        const int* __restrict__ ei,
                        const float* __restrict__ W,
                        const float* __restrict__ bias,
                        float* __restrict__ out,
                        int n_tiles)
{
  __shared__ __align__(16) unsigned short hs[WPB][TILE * ROWS];
  __shared__ __align__(16) int eis[WPB][TILE * 32];
  const int wave = threadIdx.x >> 6;
  const int lane = threadIdx.x & 63;
  const int c = lane & 15;     // MFMA col / feature chunk
  const int g = lane >> 4;     // MFMA quad group

  // ---- B fragments: W (fp32 -> bf16), resident in VGPRs.
  // B layout for mfma_f32_16x16x32_bf16: lane holds B[k=(l>>4)*8+j][n=l&15].
  short8 bfrag[4][4];
  #pragma unroll
  for (int ks = 0; ks < 4; ++ks) {
    #pragma unroll
    for (int nt = 0; nt < 4; ++nt) {
      short8 v;
      #pragma unroll
      for (int j = 0; j < 8; ++j) {
        int k = ks * 32 + g * 8 + j;
        v[j] = (short)f2bf(W[k * 64 + nt * 16 + c]);
      }
      bfrag[ks][nt] = v;
    }
  }

  const int tile = blockIdx.x * WPB + wave;
  if (tile >= n_tiles) return;
  const int node0 = tile * TILE;
  unsigned short* hrow = &hs[wave][0];

  // ---- stage this tile's 512 indices into LDS (one coalesced 2KB load)
  {
    const int4* src = (const int4*)(ei + (size_t)node0 * 32);
    int4 v0 = src[lane * 2];
    int4 v1 = src[lane * 2 + 1];
    *(int4*)&eis[wave][lane * 8] = v0;
    *(int4*)&eis[wave][lane * 8 + 4] = v1;
  }
  __asm__ volatile("s_waitcnt lgkmcnt(0)" ::: "memory");

  // ---- Phase A: 2 nodes in flight (t2), 4 neighbor-slots (h), 8 chunks (e)
  const int t2 = lane >> 5;
  const int h  = (lane >> 3) & 3;
  const int e  = lane & 7;
  const float NEG = -3.4e38f;

  #pragma unroll 2
  for (int tt = 0; tt < 8; ++tt) {
    const int t = tt * 2 + t2;
    const int n = node0 + t;
    const f4 xi0 = *(const f4*)(x + (size_t)n * 64 + e * 8);
    const f4 xi1 = *(const f4*)(x + (size_t)n * 64 + e * 8 + 4);
    f4 m0 = {NEG, NEG, NEG, NEG}, m1 = {NEG, NEG, NEG, NEG};
    #pragma unroll
    for (int it = 0; it < 8; ++it) {
      const int j = eis[wave][t * 32 + it * 4 + h];
      const uint4 r = *(const uint4*)(xbf + (size_t)j * 32 + e * 4);
      m0.x = fmaxf(m0.x, bflo(r.x) - xi0.x);
      m0.y = fmaxf(m0.y, bfhi(r.x) - xi0.y);
      m0.z = fmaxf(m0.z, bflo(r.y) - xi0.z);
      m0.w = fmaxf(m0.w, bfhi(r.y) - xi0.w);
      m1.x = fmaxf(m1.x, bflo(r.z) - xi1.x);
      m1.y = fmaxf(m1.y, bfhi(r.z) - xi1.y);
      m1.z = fmaxf(m1.z, bflo(r.w) - xi1.z);
      m1.w = fmaxf(m1.w, bfhi(r.w) - xi1.w);
    }
    // butterfly max across the 4 h-slots (lane bits 3,4)
    m0.x = fmaxf(m0.x, __shfl_xor(m0.x, 8));
    m0.y = fmaxf(m0.y, __shfl_xor(m0.y, 8));
    m0.z = fmaxf(m0.z, __shfl_xor(m0.z, 8));
    m0.w = fmaxf(m0.w, __shfl_xor(m0.w, 8));
    m1.x = fmaxf(m1.x, __shfl_xor(m1.x, 8));
    m1.y = fmaxf(m1.y, __shfl_xor(m1.y, 8));
    m1.z = fmaxf(m1.z, __shfl_xor(m1.z, 8));
    m1.w = fmaxf(m1.w, __shfl_xor(m1.w, 8));
    m0.x = fmaxf(m0.x, __shfl_xor(m0.x, 16));
    m0.y = fmaxf(m0.y, __shfl_xor(m0.y, 16));
    m0.z = fmaxf(m0.z, __shfl_xor(m0.z, 16));
    m0.w = fmaxf(m0.w, __shfl_xor(m0.w, 16));
    m1.x = fmaxf(m1.x, __shfl_xor(m1.x, 16));
    m1.y = fmaxf(m1.y, __shfl_xor(m1.y, 16));
    m1.z = fmaxf(m1.z, __shfl_xor(m1.z, 16));
    m1.w = fmaxf(m1.w, __shfl_xor(m1.w, 16));

    if (h == 0) {            // diff half of h row t
      uint4 w;
      w.x = pack2(m0.x, m0.y); w.y = pack2(m0.z, m0.w);
      w.z = pack2(m1.x, m1.y); w.w = pack2(m1.z, m1.w);
      *(uint4*)(hrow + t * ROWS + 64 + e * 8) = w;
    } else if (h == 1) {     // x half of h row t
      uint4 w;
      w.x = pack2(xi0.x, xi0.y); w.y = pack2(xi0.z, xi0.w);
      w.z = pack2(xi1.x, xi1.y); w.w = pack2(xi1.z, xi1.w);
      *(uint4*)(hrow + t * ROWS + e * 8) = w;
    }
  }
  __asm__ volatile("s_waitcnt lgkmcnt(0)" ::: "memory");

  // ---- Phase B: [16 x 128] @ [128 x 64] via 16 MFMAs.
  f4 acc[4] = {{0.f,0.f,0.f,0.f},{0.f,0.f,0.f,0.f},{0.f,0.f,0.f,0.f},{0.f,0.f,0.f,0.f}};
  #pragma unroll
  for (int ks = 0; ks < 4; ++ks) {
    // A layout: lane holds A[m=l&15][k=(l>>4)*8+j]
    short8 a = *(const short8*)(hrow + c * ROWS + ks * 32 + g * 8);
    #pragma unroll
    for (int nt = 0; nt < 4; ++nt)
      acc[nt] = __builtin_amdgcn_mfma_f32_16x16x32_bf16(a, bfrag[ks][nt], acc[nt], 0, 0, 0);
  }
  __asm__ volatile("s_waitcnt lgkmcnt(0)" ::: "memory");  // A-frag reads drained

  // ---- Epilogue: C layout col=lane&15, row=(lane>>4)*4+reg [m89-verified].
  // Stage the 16x64 fp32 tile in LDS (reuse hrow: 5120B >= 4096B), then
  // store 4 fully-coalesced 1KB float4 waves.
  float* otile = (float*)hrow;
  #pragma unroll
  for (int nt = 0; nt < 4; ++nt) {
    const float bb = bias[nt * 16 + c];
    #pragma unroll
    for (int j = 0; j < 4; ++j)
      otile[(g * 4 + j) * 64 + nt * 16 + c] = acc[nt][j] + bb;
  }
  __asm__ volatile("s_waitcnt lgkmcnt(0)" ::: "memory");
  const f4* ot = (const f4*)otile;
  float* obase = out + (size_t)node0 * 64;
  #pragma unroll
  for (int q = 0; q < 4; ++q)
    *(f4*)(obase + q * 256 + lane * 4) = ot[q * 64 + lane];
}

// ---- fallback (ws too small for the bf16 copy): R2's passing fp32 kernel
__global__ __launch_bounds__(256, 4)
void mrconv_fp32_kernel(const float* __restrict__ x,
                        const int* __restrict__ ei,
                        const float* __restrict__ W,
                        const float* __restrict__ bias,
                        float* __restrict__ out,
                        int n_tiles)
{
  __shared__ __align__(16) unsigned short hs[WPB][TILE * ROWS];
  const int wave = threadIdx.x >> 6;
  const int lane = threadIdx.x & 63;
  const int c = lane & 15;
  const int g = lane >> 4;

  short8 bfrag[4][4];
  #pragma unroll
  for (int ks = 0; ks < 4; ++ks) {
    #pragma unroll
    for (int nt = 0; nt < 4; ++nt) {
      short8 v;
      #pragma unroll
      for (int j = 0; j < 8; ++j) {
        int k = ks * 32 + g * 8 + j;
        v[j] = (short)f2bf(W[k * 64 + nt * 16 + c]);
      }
      bfrag[ks][nt] = v;
    }
  }

  const int tile = blockIdx.x * WPB + wave;
  if (tile >= n_tiles) return;
  const int node0 = tile * TILE;
  unsigned short* hrow = &hs[wave][0];

  #pragma unroll 2
  for (int t = 0; t < TILE; ++t) {
    const int n = node0 + t;
    const f4 xi = *(const f4*)(x + (size_t)n * 64 + 4 * c);
    f4 m = { -3.4e38f, -3.4e38f, -3.4e38f, -3.4e38f };
    #pragma unroll
    for (int it = 0; it < 8; ++it) {
      const int j = ei[(size_t)n * 32 + it * 4 + g];
      const f4 xj = *(const f4*)(x + (size_t)j * 64 + 4 * c);
      m.x = fmaxf(m.x, xj.x - xi.x);
      m.y = fmaxf(m.y, xj.y - xi.y);
      m.z = fmaxf(m.z, xj.z - xi.z);
      m.w = fmaxf(m.w, xj.w - xi.w);
    }
    m.x = fmaxf(m.x, __shfl_xor(m.x, 16));
    m.y = fmaxf(m.y, __shfl_xor(m.y, 16));
    m.z = fmaxf(m.z, __shfl_xor(m.z, 16));
    m.w = fmaxf(m.w, __shfl_xor(m.w, 16));
    m.x = fmaxf(m.x, __shfl_xor(m.x, 32));
    m.y = fmaxf(m.y, __shfl_xor(m.y, 32));
    m.z = fmaxf(m.z, __shfl_xor(m.z, 32));
    m.w = fmaxf(m.w, __shfl_xor(m.w, 32));
    if (g == 0) {
      ushort4 p;
      p.x = f2bf(xi.x); p.y = f2bf(xi.y); p.z = f2bf(xi.z); p.w = f2bf(xi.w);
      *(ushort4*)(hrow + t * ROWS + 4 * c) = p;
    } else if (g == 1) {
      ushort4 p;
      p.x = f2bf(m.x); p.y = f2bf(m.y); p.z = f2bf(m.z); p.w = f2bf(m.w);
      *(ushort4*)(hrow + t * ROWS + 64 + 4 * c) = p;
    }
  }
  __asm__ volatile("s_waitcnt lgkmcnt(0)" ::: "memory");

  f4 acc[4] = {{0.f,0.f,0.f,0.f},{0.f,0.f,0.f,0.f},{0.f,0.f,0.f,0.f},{0.f,0.f,0.f,0.f}};
  #pragma unroll
  for (int ks = 0; ks < 4; ++ks) {
    short8 a = *(const short8*)(hrow + c * ROWS + ks * 32 + g * 8);
    #pragma unroll
    for (int nt = 0; nt < 4; ++nt)
      acc[nt] = __builtin_amdgcn_mfma_f32_16x16x32_bf16(a, bfrag[ks][nt], acc[nt], 0, 0, 0);
  }
  const int rbase = node0 + g * 4;
  #pragma unroll
  for (int nt = 0; nt < 4; ++nt) {
    const float bb = bias[nt * 16 + c];
    #pragma unroll
    for (int j = 0; j < 4; ++j)
      out[(size_t)(rbase + j) * 64 + nt * 16 + c] = acc[nt][j] + bb;
  }
}

extern "C" void kernel_launch(void* const* d_in, const int* in_sizes, int n_in,
                              void* d_out, int out_size, void* d_ws, size_t ws_size,
                              hipStream_t stream) {
  const float* x  = (const float*)d_in[0];
  const int*   ei = (const int*)d_in[1];     // int64 in reference -> int32 here
  const float* W  = (const float*)d_in[2];
  const float* b  = (const float*)d_in[3];
  float* out = (float*)d_out;

  const int N = in_sizes[0] / 64;            // 100000
  const int n_tiles = N / TILE;              // 6250
  const int blocks = (n_tiles + WPB - 1) / WPB;

  const size_t need = (size_t)N * 64 * 2;    // bf16 copy of x: 12.8 MB
  if (ws_size >= need) {
    unsigned int* xbf = (unsigned int*)d_ws;
    const int n8 = N * 64 / 8;               // 800000 threads, 8 elems each
    hipLaunchKernelGGL(convert_kernel, dim3((n8 + 255) / 256), dim3(256), 0, stream,
                       x, xbf, n8);
    hipLaunchKernelGGL(mrconv_bf16_kernel, dim3(blocks), dim3(256), 0, stream,
                       x, xbf, ei, W, b, out, n_tiles);
  } else {
    hipLaunchKernelGGL(mrconv_fp32_kernel, dim3(blocks), dim3(256), 0, stream,
                       x, ei, W, b, out, n_tiles);
  }
}

// Round 4
// 135.656 us; speedup vs baseline: 1.9886x; 1.3967x over previous
//
#include <hip/hip_runtime.h>
#include <hip/hip_bf16.h>
#include <cstdint>

// DenseMRConv: out = concat([x, max_k(x[idx[n,k]] - x[n])]) @ W + b
// N=100000, K=32, d=64, d_out=64.
//
// R4: one block per 16-node tile (grid 6250, was 1563) to fix 33% occupancy.
// 4 waves/block: wave w gathers nodes [w*4, w*4+4) and computes MFMA column
// stripe nt=w (B-frag down to 16 VGPRs/wave). All gathers hit a bf16 copy of
// x (xbf, built by convert_kernel into d_ws) — including x_i, so the x-half
// of h is a raw bf16 copy. Epilogue: one coalesced 4KB block store via LDS.

typedef __attribute__((ext_vector_type(8))) short short8;
typedef __attribute__((ext_vector_type(4))) float f4;

#define TILE 16
#define ROWS 168   // padded h row stride in bf16 elems (336 B = 21*16, 16B-aligned)

__device__ __forceinline__ unsigned short f2bf(float f) {
  unsigned int u = __builtin_bit_cast(unsigned int, f);
  u += 0x7fffu + ((u >> 16) & 1u);          // round-to-nearest-even
  return (unsigned short)(u >> 16);
}
__device__ __forceinline__ unsigned int pack2(float a, float b) {
  return (unsigned int)f2bf(a) | ((unsigned int)f2bf(b) << 16);
}
__device__ __forceinline__ float bflo(unsigned int u) {
  return __builtin_bit_cast(float, u << 16);
}
__device__ __forceinline__ float bfhi(unsigned int u) {
  return __builtin_bit_cast(float, u & 0xffff0000u);
}

// ---- pass 1: x fp32 -> bf16 copy in workspace (each thread: 8 elems)
__global__ __launch_bounds__(256)
void convert_kernel(const float* __restrict__ x, unsigned int* __restrict__ xbf, int n8) {
  int i = blockIdx.x * 256 + threadIdx.x;
  if (i >= n8) return;
  const f4* p = (const f4*)x + (size_t)i * 2;
  f4 a = p[0], b = p[1];
  uint4 w;
  w.x = pack2(a.x, a.y); w.y = pack2(a.z, a.w);
  w.z = pack2(b.x, b.y); w.w = pack2(b.z, b.w);
  ((uint4*)xbf)[i] = w;
}

// ---- pass 2: gather + max + MFMA GEMM. One block per 16-node tile.
__global__ __launch_bounds__(256, 6)
void mrconv2_kernel(const unsigned int* __restrict__ xbf,  // 2 bf16 per uint
                    const int* __restrict__ ei,
                    const float* __restrict__ W,
                    const float* __restrict__ bias,
                    float* __restrict__ out,
                    int n_tiles)
{
  __shared__ __align__(16) unsigned short hs[TILE * ROWS];
  __shared__ __align__(16) int eis[TILE * 32];
  __shared__ __align__(16) float otile[TILE * 64];

  const int tid  = threadIdx.x;
  const int wv   = tid >> 6;
  const int lane = tid & 63;
  const int c = lane & 15;         // MFMA col / m-row selector
  const int g = lane >> 4;         // MFMA quad group
  const int t2 = lane >> 5;        // node parity within pair
  const int h  = (lane >> 3) & 3;  // neighbor slot
  const int e  = lane & 7;         // 16B feature chunk of bf16 row

  const int node0 = blockIdx.x * TILE;

  // ---- B fragment: wave w owns output columns [w*16, w*16+16).
  // B layout for mfma_f32_16x16x32_bf16: lane holds B[k=(l>>4)*8+j][n=l&15].
  short8 bfrag[4];
  #pragma unroll
  for (int ks = 0; ks < 4; ++ks) {
    short8 v;
    #pragma unroll
    for (int j = 0; j < 8; ++j)
      v[j] = (short)f2bf(W[(ks * 32 + g * 8 + j) * 64 + wv * 16 + c]);
    bfrag[ks] = v;
  }

  // ---- stage this tile's 512 indices (2KB, one coalesced load)
  *(int2*)&eis[tid * 2] = *(const int2*)(ei + (size_t)node0 * 32 + tid * 2);
  __syncthreads();

  // ---- Phase A: wave w handles nodes w*4 .. w*4+3 (2 per tt step)
  const float NEG = -3.4e38f;
  #pragma unroll
  for (int tt = 0; tt < 2; ++tt) {
    const int t = wv * 4 + tt * 2 + t2;
    const uint4 xr = *(const uint4*)(xbf + (size_t)(node0 + t) * 32 + e * 4);
    const float xi0 = bflo(xr.x), xi1 = bfhi(xr.x);
    const float xi2 = bflo(xr.y), xi3 = bfhi(xr.y);
    const float xi4 = bflo(xr.z), xi5 = bfhi(xr.z);
    const float xi6 = bflo(xr.w), xi7 = bfhi(xr.w);
    float m0 = NEG, m1 = NEG, m2 = NEG, m3 = NEG;
    float m4 = NEG, m5 = NEG, m6 = NEG, m7 = NEG;
    #pragma unroll
    for (int it = 0; it < 8; ++it) {
      const int j = eis[t * 32 + it * 4 + h];
      const uint4 r = *(const uint4*)(xbf + (size_t)j * 32 + e * 4);
      m0 = fmaxf(m0, bflo(r.x) - xi0);
      m1 = fmaxf(m1, bfhi(r.x) - xi1);
      m2 = fmaxf(m2, bflo(r.y) - xi2);
      m3 = fmaxf(m3, bfhi(r.y) - xi3);
      m4 = fmaxf(m4, bflo(r.z) - xi4);
      m5 = fmaxf(m5, bfhi(r.z) - xi5);
      m6 = fmaxf(m6, bflo(r.w) - xi6);
      m7 = fmaxf(m7, bfhi(r.w) - xi7);
    }
    // reduce over the 4 h-slots (lane bits 3 and 4)
    m0 = fmaxf(m0, __shfl_xor(m0, 8));  m1 = fmaxf(m1, __shfl_xor(m1, 8));
    m2 = fmaxf(m2, __shfl_xor(m2, 8));  m3 = fmaxf(m3, __shfl_xor(m3, 8));
    m4 = fmaxf(m4, __shfl_xor(m4, 8));  m5 = fmaxf(m5, __shfl_xor(m5, 8));
    m6 = fmaxf(m6, __shfl_xor(m6, 8));  m7 = fmaxf(m7, __shfl_xor(m7, 8));
    m0 = fmaxf(m0, __shfl_xor(m0, 16)); m1 = fmaxf(m1, __shfl_xor(m1, 16));
    m2 = fmaxf(m2, __shfl_xor(m2, 16)); m3 = fmaxf(m3, __shfl_xor(m3, 16));
    m4 = fmaxf(m4, __shfl_xor(m4, 16)); m5 = fmaxf(m5, __shfl_xor(m5, 16));
    m6 = fmaxf(m6, __shfl_xor(m6, 16)); m7 = fmaxf(m7, __shfl_xor(m7, 16));

    if (h == 1) {          // x half: raw bf16 copy, no repack
      *(uint4*)(hs + t * ROWS + e * 8) = xr;
    } else if (h == 0) {   // diff half
      uint4 w;
      w.x = pack2(m0, m1); w.y = pack2(m2, m3);
      w.z = pack2(m4, m5); w.w = pack2(m6, m7);
      *(uint4*)(hs + t * ROWS + 64 + e * 8) = w;
    }
  }
  __syncthreads();

  // ---- Phase B: wave w computes C[:, w*16 : w*16+16] via 4 MFMAs.
  f4 acc = {0.f, 0.f, 0.f, 0.f};
  #pragma unroll
  for (int ks = 0; ks < 4; ++ks) {
    // A layout: lane holds A[m=l&15][k=(l>>4)*8+j]
    short8 a = *(const short8*)(hs + c * ROWS + ks * 32 + g * 8);
    acc = __builtin_amdgcn_mfma_f32_16x16x32_bf16(a, bfrag[ks], acc, 0, 0, 0);
  }

  // ---- Epilogue: C layout col=lane&15, row=(lane>>4)*4+reg [m89-verified].
  const float bb = bias[wv * 16 + c];
  #pragma unroll
  for (int j = 0; j < 4; ++j)
    otile[(g * 4 + j) * 64 + wv * 16 + c] = acc[j] + bb;
  __syncthreads();
  *(f4*)(out + (size_t)node0 * 64 + tid * 4) = *(const f4*)&otile[tid * 4];
}

// ---- fallback (ws too small for the bf16 copy): R2's proven fp32 kernel
#define FWPB 4
#define FROWS 160
__global__ __launch_bounds__(256, 4)
void mrconv_fp32_kernel(const float* __restrict__ x,
                        const int* __restrict__ ei,
                        const float* __restrict__ W,
                        const float* __restrict__ bias,
                        float* __restrict__ out,
                        int n_tiles)
{
  __shared__ __align__(16) unsigned short hsf[FWPB][TILE * FROWS];
  const int wave = threadIdx.x >> 6;
  const int lane = threadIdx.x & 63;
  const int c = lane & 15;
  const int g = lane >> 4;

  short8 bfrag[4][4];
  #pragma unroll
  for (int ks = 0; ks < 4; ++ks) {
    #pragma unroll
    for (int nt = 0; nt < 4; ++nt) {
      short8 v;
      #pragma unroll
      for (int j = 0; j < 8; ++j) {
        int k = ks * 32 + g * 8 + j;
        v[j] = (short)f2bf(W[k * 64 + nt * 16 + c]);
      }
      bfrag[ks][nt] = v;
    }
  }

  const int tile = blockIdx.x * FWPB + wave;
  if (tile >= n_tiles) return;
  const int node0 = tile * TILE;
  unsigned short* hrow = &hsf[wave][0];

  #pragma unroll 2
  for (int t = 0; t < TILE; ++t) {
    const int n = node0 + t;
    const f4 xi = *(const f4*)(x + (size_t)n * 64 + 4 * c);
    f4 m = { -3.4e38f, -3.4e38f, -3.4e38f, -3.4e38f };
    #pragma unroll
    for (int it = 0; it < 8; ++it) {
      const int j = ei[(size_t)n * 32 + it * 4 + g];
      const f4 xj = *(const f4*)(x + (size_t)j * 64 + 4 * c);
      m.x = fmaxf(m.x, xj.x - xi.x);
      m.y = fmaxf(m.y, xj.y - xi.y);
      m.z = fmaxf(m.z, xj.z - xi.z);
      m.w = fmaxf(m.w, xj.w - xi.w);
    }
    m.x = fmaxf(m.x, __shfl_xor(m.x, 16));
    m.y = fmaxf(m.y, __shfl_xor(m.y, 16));
    m.z = fmaxf(m.z, __shfl_xor(m.z, 16));
    m.w = fmaxf(m.w, __shfl_xor(m.w, 16));
    m.x = fmaxf(m.x, __shfl_xor(m.x, 32));
    m.y = fmaxf(m.y, __shfl_xor(m.y, 32));
    m.z = fmaxf(m.z, __shfl_xor(m.z, 32));
    m.w = fmaxf(m.w, __shfl_xor(m.w, 32));
    if (g == 0) {
      ushort4 p;
      p.x = f2bf(xi.x); p.y = f2bf(xi.y); p.z = f2bf(xi.z); p.w = f2bf(xi.w);
      *(ushort4*)(hrow + t * FROWS + 4 * c) = p;
    } else if (g == 1) {
      ushort4 p;
      p.x = f2bf(m.x); p.y = f2bf(m.y); p.z = f2bf(m.z); p.w = f2bf(m.w);
      *(ushort4*)(hrow + t * FROWS + 64 + 4 * c) = p;
    }
  }
  __asm__ volatile("s_waitcnt lgkmcnt(0)" ::: "memory");

  f4 acc[4] = {{0.f,0.f,0.f,0.f},{0.f,0.f,0.f,0.f},{0.f,0.f,0.f,0.f},{0.f,0.f,0.f,0.f}};
  #pragma unroll
  for (int ks = 0; ks < 4; ++ks) {
    short8 a = *(const short8*)(hrow + c * FROWS + ks * 32 + g * 8);
    #pragma unroll
    for (int nt = 0; nt < 4; ++nt)
      acc[nt] = __builtin_amdgcn_mfma_f32_16x16x32_bf16(a, bfrag[ks][nt], acc[nt], 0, 0, 0);
  }
  const int rbase = node0 + g * 4;
  #pragma unroll
  for (int nt = 0; nt < 4; ++nt) {
    const float bb = bias[nt * 16 + c];
    #pragma unroll
    for (int j = 0; j < 4; ++j)
      out[(size_t)(rbase + j) * 64 + nt * 16 + c] = acc[nt][j] + bb;
  }
}

extern "C" void kernel_launch(void* const* d_in, const int* in_sizes, int n_in,
                              void* d_out, int out_size, void* d_ws, size_t ws_size,
                              hipStream_t stream) {
  const float* x  = (const float*)d_in[0];
  const int*   ei = (const int*)d_in[1];     // int64 in reference -> int32 here
  const float* W  = (const float*)d_in[2];
  const float* b  = (const float*)d_in[3];
  float* out = (float*)d_out;

  const int N = in_sizes[0] / 64;            // 100000
  const int n_tiles = N / TILE;              // 6250

  const size_t need = (size_t)N * 64 * 2;    // bf16 copy of x: 12.8 MB
  if (ws_size >= need) {
    unsigned int* xbf = (unsigned int*)d_ws;
    const int n8 = N * 64 / 8;
    hipLaunchKernelGGL(convert_kernel, dim3((n8 + 255) / 256), dim3(256), 0, stream,
                       x, xbf, n8);
    hipLaunchKernelGGL(mrconv2_kernel, dim3(n_tiles), dim3(256), 0, stream,
                       xbf, ei, W, b, out, n_tiles);
  } else {
    const int blocks = (n_tiles + FWPB - 1) / FWPB;
    hipLaunchKernelGGL(mrconv_fp32_kernel, dim3(blocks), dim3(256), 0, stream,
                       x, ei, W, b, out, n_tiles);
  }
}

// Round 5
// 130.600 us; speedup vs baseline: 2.0656x; 1.0387x over previous
//
#include <hip/hip_runtime.h>
#include <hip/hip_bf16.h>
#include <cstdint>

// DenseMRConv: out = concat([x, max_k(x[idx[n,k]] - x[n])]) @ W + b
// N=100000, K=32, d=64, d_out=64.
//
// R5: (a) max-first: max_k(x_j - x_i) == (max_k x_j) - x_i, so the subtract
// leaves the 32-deep gather loop; loop body is unpack+max only, paired for
// v_max3_f32. (b) lanes = 4 nodes x 2 slots x 8 chunks -> 16 independent
// gathers in flight per lane, single shuffle-reduce round. (c) W bf16 MFMA
// fragments precomputed into ws by the convert pass; each wave loads 4
// coalesced dwordx4 instead of 32 strided scalars per block.

typedef __attribute__((ext_vector_type(8))) short short8;
typedef __attribute__((ext_vector_type(4))) float f4;

#define TILE 16
#define ROWS 168   // padded h row stride in bf16 elems (336 B, 16B-aligned)

__device__ __forceinline__ unsigned short f2bf(float f) {
  unsigned int u = __builtin_bit_cast(unsigned int, f);
  u += 0x7fffu + ((u >> 16) & 1u);          // round-to-nearest-even
  return (unsigned short)(u >> 16);
}
__device__ __forceinline__ unsigned int pack2(float a, float b) {
  return (unsigned int)f2bf(a) | ((unsigned int)f2bf(b) << 16);
}
__device__ __forceinline__ float bflo(unsigned int u) {
  return __builtin_bit_cast(float, u << 16);
}
__device__ __forceinline__ float bfhi(unsigned int u) {
  return __builtin_bit_cast(float, u & 0xffff0000u);
}

// ---- pass 1: x -> bf16 copy (blocks [0,nxb)), W -> MFMA B-frags (block nxb)
__global__ __launch_bounds__(256)
void convert_kernel(const float* __restrict__ x, unsigned int* __restrict__ xbf,
                    const float* __restrict__ W, unsigned short* __restrict__ wf,
                    int n8, int nxb) {
  if ((int)blockIdx.x < nxb) {
    int i = blockIdx.x * 256 + threadIdx.x;
    if (i >= n8) return;
    const f4* p = (const f4*)x + (size_t)i * 2;
    f4 a = p[0], b = p[1];
    uint4 w;
    w.x = pack2(a.x, a.y); w.y = pack2(a.z, a.w);
    w.z = pack2(b.x, b.y); w.w = pack2(b.z, b.w);
    ((uint4*)xbf)[i] = w;
  } else {
    // 1024 short8 entries: entry (wv,ks,l) = B-frag for wave wv, k-slab ks.
    // B layout for mfma_f32_16x16x32_bf16: lane holds B[k=(l>>4)*8+j][n=l&15].
    #pragma unroll
    for (int q = 0; q < 4; ++q) {
      int idx = threadIdx.x * 4 + q;
      int wv = idx >> 8, ks = (idx >> 6) & 3, l = idx & 63;
      int c = l & 15, g = l >> 4;
      short8 v;
      #pragma unroll
      for (int j = 0; j < 8; ++j)
        v[j] = (short)f2bf(W[(ks * 32 + g * 8 + j) * 64 + wv * 16 + c]);
      *(short8*)(wf + (size_t)idx * 8) = v;
    }
  }
}

// ---- pass 2: gather + max + MFMA GEMM. One block per 16-node tile.
__global__ __launch_bounds__(256, 6)
void mrconv3_kernel(const unsigned int* __restrict__ xbf,  // 2 bf16 per uint
                    const unsigned short* __restrict__ wf, // prebuilt B-frags
                    const int* __restrict__ ei,
                    const float* __restrict__ bias,
                    float* __restrict__ out,
                    int n_tiles)
{
  __shared__ __align__(16) unsigned short hs[TILE * ROWS];
  __shared__ __align__(16) int eis[TILE * 32];
  __shared__ __align__(16) float otile[TILE * 64];

  const int tid  = threadIdx.x;
  const int wv   = tid >> 6;
  const int lane = tid & 63;
  const int c = lane & 15;         // MFMA col / m-row selector
  const int g = lane >> 4;         // MFMA quad group
  const int t2 = lane >> 4;        // which of this wave's 4 nodes
  const int h  = (lane >> 3) & 1;  // neighbor half (16 each)
  const int e  = lane & 7;         // 16B feature chunk

  const int node0 = blockIdx.x * TILE;
  const int t = wv * 4 + t2;       // node row within tile

  // ---- B fragments: 4 coalesced 16B loads from the prebuilt table.
  short8 bfrag[4];
  #pragma unroll
  for (int ks = 0; ks < 4; ++ks)
    bfrag[ks] = *(const short8*)(wf + (size_t)((wv * 4 + ks) * 64 + lane) * 8);

  // ---- stage this tile's 512 indices (2KB, one coalesced load)
  *(int2*)&eis[tid * 2] = *(const int2*)(ei + (size_t)node0 * 32 + tid * 2);
  __syncthreads();

  // ---- Phase A: max-first over 16 gathers/lane, paired for v_max3.
  const float NEG = -3.4e38f;
  const uint4 xr = *(const uint4*)(xbf + (size_t)(node0 + t) * 32 + e * 4);
  float l0 = NEG, h0 = NEG, l1 = NEG, h1 = NEG;
  float l2 = NEG, h2 = NEG, l3 = NEG, h3 = NEG;
  #pragma unroll
  for (int it = 0; it < 16; it += 2) {
    const int ja = eis[t * 32 + it * 2 + h];
    const int jb = eis[t * 32 + it * 2 + 2 + h];
    const uint4 ra = *(const uint4*)(xbf + (size_t)ja * 32 + e * 4);
    const uint4 rb = *(const uint4*)(xbf + (size_t)jb * 32 + e * 4);
    l0 = fmaxf(l0, fmaxf(bflo(ra.x), bflo(rb.x)));
    h0 = fmaxf(h0, fmaxf(bfhi(ra.x), bfhi(rb.x)));
    l1 = fmaxf(l1, fmaxf(bflo(ra.y), bflo(rb.y)));
    h1 = fmaxf(h1, fmaxf(bfhi(ra.y), bfhi(rb.y)));
    l2 = fmaxf(l2, fmaxf(bflo(ra.z), bflo(rb.z)));
    h2 = fmaxf(h2, fmaxf(bfhi(ra.z), bfhi(rb.z)));
    l3 = fmaxf(l3, fmaxf(bflo(ra.w), bflo(rb.w)));
    h3 = fmaxf(h3, fmaxf(bfhi(ra.w), bfhi(rb.w)));
  }
  // reduce the h-pair (lane bit 3)
  l0 = fmaxf(l0, __shfl_xor(l0, 8));  h0 = fmaxf(h0, __shfl_xor(h0, 8));
  l1 = fmaxf(l1, __shfl_xor(l1, 8));  h1 = fmaxf(h1, __shfl_xor(h1, 8));
  l2 = fmaxf(l2, __shfl_xor(l2, 8));  h2 = fmaxf(h2, __shfl_xor(h2, 8));
  l3 = fmaxf(l3, __shfl_xor(l3, 8));  h3 = fmaxf(h3, __shfl_xor(h3, 8));

  if (h == 0) {            // diff half: (max x_j) - x_i
    uint4 w;
    w.x = pack2(l0 - bflo(xr.x), h0 - bfhi(xr.x));
    w.y = pack2(l1 - bflo(xr.y), h1 - bfhi(xr.y));
    w.z = pack2(l2 - bflo(xr.z), h2 - bfhi(xr.z));
    w.w = pack2(l3 - bflo(xr.w), h3 - bfhi(xr.w));
    *(uint4*)(hs + t * ROWS + 64 + e * 8) = w;
  } else {                 // x half: raw bf16 copy
    *(uint4*)(hs + t * ROWS + e * 8) = xr;
  }
  __syncthreads();

  // ---- Phase B: wave wv computes C[:, wv*16 : wv*16+16] via 4 MFMAs.
  f4 acc = {0.f, 0.f, 0.f, 0.f};
  #pragma unroll
  for (int ks = 0; ks < 4; ++ks) {
    // A layout: lane holds A[m=l&15][k=(l>>4)*8+j]
    short8 a = *(const short8*)(hs + c * ROWS + ks * 32 + g * 8);
    acc = __builtin_amdgcn_mfma_f32_16x16x32_bf16(a, bfrag[ks], acc, 0, 0, 0);
  }

  // ---- Epilogue: C layout col=lane&15, row=(lane>>4)*4+reg [m89-verified].
  const float bb = bias[wv * 16 + c];
  #pragma unroll
  for (int j = 0; j < 4; ++j)
    otile[(g * 4 + j) * 64 + wv * 16 + c] = acc[j] + bb;
  __syncthreads();
  *(f4*)(out + (size_t)node0 * 64 + tid * 4) = *(const f4*)&otile[tid * 4];
}

// ---- fallback (ws too small): R2's proven fp32 kernel
#define FWPB 4
#define FROWS 160
__global__ __launch_bounds__(256, 4)
void mrconv_fp32_kernel(const float* __restrict__ x,
                        const int* __restrict__ ei,
                        const float* __restrict__ W,
                        const float* __restrict__ bias,
                        float* __restrict__ out,
                        int n_tiles)
{
  __shared__ __align__(16) unsigned short hsf[FWPB][TILE * FROWS];
  const int wave = threadIdx.x >> 6;
  const int lane = threadIdx.x & 63;
  const int c = lane & 15;
  const int g = lane >> 4;

  short8 bfrag[4][4];
  #pragma unroll
  for (int ks = 0; ks < 4; ++ks) {
    #pragma unroll
    for (int nt = 0; nt < 4; ++nt) {
      short8 v;
      #pragma unroll
      for (int j = 0; j < 8; ++j) {
        int k = ks * 32 + g * 8 + j;
        v[j] = (short)f2bf(W[k * 64 + nt * 16 + c]);
      }
      bfrag[ks][nt] = v;
    }
  }

  const int tile = blockIdx.x * FWPB + wave;
  if (tile >= n_tiles) return;
  const int node0 = tile * TILE;
  unsigned short* hrow = &hsf[wave][0];

  #pragma unroll 2
  for (int t = 0; t < TILE; ++t) {
    const int n = node0 + t;
    const f4 xi = *(const f4*)(x + (size_t)n * 64 + 4 * c);
    f4 m = { -3.4e38f, -3.4e38f, -3.4e38f, -3.4e38f };
    #pragma unroll
    for (int it = 0; it < 8; ++it) {
      const int j = ei[(size_t)n * 32 + it * 4 + g];
      const f4 xj = *(const f4*)(x + (size_t)j * 64 + 4 * c);
      m.x = fmaxf(m.x, xj.x - xi.x);
      m.y = fmaxf(m.y, xj.y - xi.y);
      m.z = fmaxf(m.z, xj.z - xi.z);
      m.w = fmaxf(m.w, xj.w - xi.w);
    }
    m.x = fmaxf(m.x, __shfl_xor(m.x, 16));
    m.y = fmaxf(m.y, __shfl_xor(m.y, 16));
    m.z = fmaxf(m.z, __shfl_xor(m.z, 16));
    m.w = fmaxf(m.w, __shfl_xor(m.w, 16));
    m.x = fmaxf(m.x, __shfl_xor(m.x, 32));
    m.y = fmaxf(m.y, __shfl_xor(m.y, 32));
    m.z = fmaxf(m.z, __shfl_xor(m.z, 32));
    m.w = fmaxf(m.w, __shfl_xor(m.w, 32));
    if (g == 0) {
      ushort4 p;
      p.x = f2bf(xi.x); p.y = f2bf(xi.y); p.z = f2bf(xi.z); p.w = f2bf(xi.w);
      *(ushort4*)(hrow + t * FROWS + 4 * c) = p;
    } else if (g == 1) {
      ushort4 p;
      p.x = f2bf(m.x); p.y = f2bf(m.y); p.z = f2bf(m.z); p.w = f2bf(m.w);
      *(ushort4*)(hrow + t * FROWS + 64 + 4 * c) = p;
    }
  }
  __asm__ volatile("s_waitcnt lgkmcnt(0)" ::: "memory");

  f4 acc[4] = {{0.f,0.f,0.f,0.f},{0.f,0.f,0.f,0.f},{0.f,0.f,0.f,0.f},{0.f,0.f,0.f,0.f}};
  #pragma unroll
  for (int ks = 0; ks < 4; ++ks) {
    short8 a = *(const short8*)(hrow + c * FROWS + ks * 32 + g * 8);
    #pragma unroll
    for (int nt = 0; nt < 4; ++nt)
      acc[nt] = __builtin_amdgcn_mfma_f32_16x16x32_bf16(a, bfrag[ks][nt], acc[nt], 0, 0, 0);
  }
  const int rbase = node0 + g * 4;
  #pragma unroll
  for (int nt = 0; nt < 4; ++nt) {
    const float bb = bias[nt * 16 + c];
    #pragma unroll
    for (int j = 0; j < 4; ++j)
      out[(size_t)(rbase + j) * 64 + nt * 16 + c] = acc[nt][j] + bb;
  }
}

extern "C" void kernel_launch(void* const* d_in, const int* in_sizes, int n_in,
                              void* d_out, int out_size, void* d_ws, size_t ws_size,
                              hipStream_t stream) {
  const float* x  = (const float*)d_in[0];
  const int*   ei = (const int*)d_in[1];     // int64 in reference -> int32 here
  const float* W  = (const float*)d_in[2];
  const float* b  = (const float*)d_in[3];
  float* out = (float*)d_out;

  const int N = in_sizes[0] / 64;            // 100000
  const int n_tiles = N / TILE;              // 6250

  const size_t xbf_bytes = (size_t)N * 64 * 2;   // 12.8 MB
  const size_t wf_bytes  = 1024 * 16;            // 16 KB of B-frags
  if (ws_size >= xbf_bytes + wf_bytes) {
    unsigned int*   xbf = (unsigned int*)d_ws;
    unsigned short* wf  = (unsigned short*)((char*)d_ws + xbf_bytes);
    const int n8  = N * 64 / 8;                  // 800000
    const int nxb = (n8 + 255) / 256;            // 3125
    hipLaunchKernelGGL(convert_kernel, dim3(nxb + 1), dim3(256), 0, stream,
                       x, xbf, W, wf, n8, nxb);
    hipLaunchKernelGGL(mrconv3_kernel, dim3(n_tiles), dim3(256), 0, stream,
                       xbf, wf, ei, b, out, n_tiles);
  } else {
    const int blocks = (n_tiles + FWPB - 1) / FWPB;
    hipLaunchKernelGGL(mrconv_fp32_kernel, dim3(blocks), dim3(256), 0, stream,
                       x, ei, W, b, out, n_tiles);
  }
}